// Round 3
// baseline (189.343 us; speedup 1.0000x reference)
//
#include <hip/hip_runtime.h>
#include <hip/hip_bf16.h>

#define NBINS 600
#define NCOPIES 16  // copy = tid&15; layout h[bin*16+copy] pins each lane to ~1 bank

// Kernel A: per-block privatized LDS histogram -> plain-store partials to ws.
// No global atomics, no dependence on prior d_out/d_ws state (full overwrite of
// its ws slice every call) => idempotent under any replay overlap.
__global__ __launch_bounds__(256) void bincount_part(
        const int* __restrict__ x, int n, int* __restrict__ part) {
    __shared__ int h[NBINS * NCOPIES];  // 38400 B -> 4 blocks/CU

    for (int i = threadIdx.x; i < NBINS * NCOPIES; i += 256) h[i] = 0;
    __syncthreads();

    const int c = threadIdx.x & (NCOPIES - 1);
    const int n4 = n >> 2;
    const int4* __restrict__ x4 = (const int4*)x;
    const int stride = gridDim.x * 256;
    int i = blockIdx.x * 256 + threadIdx.x;

    // 2x unrolled: two int4 loads in flight per wave before the waitcnt
    for (; i + stride < n4; i += 2 * stride) {
        int4 a = x4[i];
        int4 b = x4[i + stride];
        atomicAdd(&h[a.x * NCOPIES + c], 1);
        atomicAdd(&h[a.y * NCOPIES + c], 1);
        atomicAdd(&h[a.z * NCOPIES + c], 1);
        atomicAdd(&h[a.w * NCOPIES + c], 1);
        atomicAdd(&h[b.x * NCOPIES + c], 1);
        atomicAdd(&h[b.y * NCOPIES + c], 1);
        atomicAdd(&h[b.z * NCOPIES + c], 1);
        atomicAdd(&h[b.w * NCOPIES + c], 1);
    }
    if (i < n4) {
        int4 a = x4[i];
        atomicAdd(&h[a.x * NCOPIES + c], 1);
        atomicAdd(&h[a.y * NCOPIES + c], 1);
        atomicAdd(&h[a.z * NCOPIES + c], 1);
        atomicAdd(&h[a.w * NCOPIES + c], 1);
    }
    // scalar tail (n % 4 != 0), block 0 only, into its own LDS hist
    if (blockIdx.x == 0) {
        for (int t = (n4 << 2) + (int)threadIdx.x; t < n; t += 256)
            atomicAdd(&h[x[t] * NCOPIES + c], 1);
    }

    __syncthreads();

    // per-block partial: rotate copy index by lane to avoid reduce-side conflicts
    for (int b = threadIdx.x; b < NBINS; b += 256) {
        int s = 0;
        #pragma unroll
        for (int j = 0; j < NCOPIES; ++j)
            s += h[b * NCOPIES + ((j + threadIdx.x) & (NCOPIES - 1))];
        part[blockIdx.x * NBINS + b] = s;  // plain store, coalesced
    }
}

// Kernel B: out[bin] = sum over block partials. Plain store, replay-invariant.
__global__ __launch_bounds__(256) void bincount_reduce(
        const int* __restrict__ part, int nblocks, int* __restrict__ out) {
    __shared__ int red[256];
    const int bin = blockIdx.x;
    int s = 0;
    for (int b = threadIdx.x; b < nblocks; b += 256)
        s += part[b * NBINS + bin];
    red[threadIdx.x] = s;
    __syncthreads();
    for (int off = 128; off > 0; off >>= 1) {
        if (threadIdx.x < off) red[threadIdx.x] += red[threadIdx.x + off];
        __syncthreads();
    }
    if (threadIdx.x == 0) out[bin] = red[0];
}

extern "C" void kernel_launch(void* const* d_in, const int* in_sizes, int n_in,
                              void* d_out, int out_size, void* d_ws, size_t ws_size,
                              hipStream_t stream) {
    const int* x = (const int*)d_in[0];
    int* out = (int*)d_out;
    int* part = (int*)d_ws;
    const int n = in_sizes[0];

    // 1024 blocks = 4/CU (LDS-limited), 16 waves/CU; shrink if ws is small.
    int nblocks = 1024;
    while ((size_t)nblocks * NBINS * sizeof(int) > ws_size && nblocks > 64)
        nblocks >>= 1;

    bincount_part<<<nblocks, 256, 0, stream>>>(x, n, part);
    bincount_reduce<<<NBINS, 256, 0, stream>>>(part, nblocks, out);
}